// Round 1
// baseline (487.450 us; speedup 1.0000x reference)
//
#include <hip/hip_runtime.h>

// CIN folded algorithm:
//   per (b,d): v = x0[b,:,d] (32)
//   h1[h]     = sum_{p,q} W1[h,p,q] v_p v_q            (+ b1 in epilogue)
//   Dt[h]     = sum_{p,q} C[h,p,q] v_p v_q + sum_m A[h,m] v_m
//   s(b,d)    = sum_h (h1[h]+b1[h]) * (w1out[h] + Dt[h]) + r.v
//   out[b]    = cnst + sum_d s(b,d)
// where (precomputed):
//   W3eff[h,m] = sum_o W_out[128+o] * W3[o,h,m]
//   C[h,m,m']  = sum_o W3eff[o,m'] * W2[o,h,m]
//   A[h,m]     = sum_o W_out[64+o] * W2[o,h,m]
//   r[m]       = sum_h b2[h] * W3eff[h,m]
//   cnst       = b_out + 64 * (b2.w2out + b3.w3out)
// GEMM form: rows=(b,d) [131072], K=1056 (v⊗v ++ v), N=128 ([W1 | C;A])

__global__ void pre_w3eff(const float* __restrict__ W3,
                          const float* __restrict__ W_out,
                          float* __restrict__ W3eff) {
    int tid = blockIdx.x * blockDim.x + threadIdx.x;  // 2048
    int h = tid >> 5, m = tid & 31;
    float s = 0.f;
    for (int o3 = 0; o3 < 64; ++o3)
        s += W_out[128 + o3] * W3[(o3 * 64 + h) * 32 + m];
    W3eff[h * 32 + m] = s;
}

__global__ void pre_wcat(const float* __restrict__ W1,
                         const float* __restrict__ W2,
                         const float* __restrict__ W_out,
                         const float* __restrict__ W3eff,
                         float* __restrict__ Wcat) {
    int tid = blockIdx.x * blockDim.x + threadIdx.x;  // 1056*128 = 135168
    int k = tid >> 7, j = tid & 127;
    float val = 0.f;
    if (k < 1024) {
        int p = k >> 5, q = k & 31;
        if (j < 64) {
            val = W1[j * 1024 + k];  // W1[j,p,q]
        } else {
            int h = j - 64;
            for (int o = 0; o < 64; ++o)
                val += W3eff[o * 32 + q] * W2[(o * 64 + h) * 32 + p];
        }
    } else {
        int mm = k - 1024;
        if (j >= 64) {
            int h = j - 64;
            for (int o = 0; o < 64; ++o)
                val += W_out[64 + o] * W2[(o * 64 + h) * 32 + mm];
        }
    }
    Wcat[k * 128 + j] = val;
}

__global__ void pre_misc(const float* __restrict__ b2,
                         const float* __restrict__ b3,
                         const float* __restrict__ W_out,
                         const float* __restrict__ b_out,
                         const float* __restrict__ W3eff,
                         float* __restrict__ rvec,
                         float* __restrict__ cnst) {
    int t = threadIdx.x;  // 64
    if (t < 32) {
        float s = 0.f;
        for (int h = 0; h < 64; ++h) s += b2[h] * W3eff[h * 32 + t];
        rvec[t] = s;
    }
    if (t == 63) {
        float s = 0.f;
        for (int o = 0; o < 64; ++o)
            s += b2[o] * W_out[64 + o] + b3[o] * W_out[128 + o];
        cnst[0] = b_out[0] + 64.f * s;
    }
}

// Main: 1 block per batch row b. 64 GEMM-rows (d=0..63) x 128 cols.
// 256 threads: thread (tr=t&15, tc=t>>4) owns rows 4tr..4tr+3, cols 8tc..8tc+7.
__global__ __launch_bounds__(256) void cin_main(
    const float* __restrict__ x0, const float* __restrict__ Wcat,
    const float* __restrict__ b1, const float* __restrict__ W_out,
    const float* __restrict__ rvec, const float* __restrict__ cnst,
    float* __restrict__ out) {
    __shared__ float x0s[32 * 64];     // x0s[m][d]
    __shared__ float shbuf[64 * 129];  // k-loop: wch[32][128]; epilogue: accs[64][129]
    __shared__ float b1s[64], w1s[64], rs[32];

    const int t = threadIdx.x;
    const int b = blockIdx.x;

    {   // stage x0[b] (32x64 fp32, contiguous)
        const float4* src = reinterpret_cast<const float4*>(x0 + (size_t)b * 2048);
        float4* dst = reinterpret_cast<float4*>(x0s);
        dst[t] = src[t];
        dst[t + 256] = src[t + 256];
    }
    if (t < 64) b1s[t] = b1[t];
    else if (t < 128) w1s[t - 64] = W_out[t - 64];
    else if (t < 160) rs[t - 128] = rvec[t - 128];

    const int tr = t & 15, tc = t >> 4;
    float acc[4][8];
#pragma unroll
    for (int i = 0; i < 4; ++i)
#pragma unroll
        for (int j = 0; j < 8; ++j) acc[i][j] = 0.f;

    for (int chunk = 0; chunk < 33; ++chunk) {
        if (chunk) __syncthreads();  // previous wch fully consumed
        {
            const float4* wsrc = reinterpret_cast<const float4*>(Wcat + chunk * 4096);
            float4* wdst = reinterpret_cast<float4*>(shbuf);
#pragma unroll
            for (int i = 0; i < 4; ++i) wdst[t + 256 * i] = wsrc[t + 256 * i];
        }
        __syncthreads();

        float a0, a1, a2, a3;
        if (chunk < 32) {  // P[d][32*chunk+q] = v[chunk]*v[q]
            const float4 av = *reinterpret_cast<const float4*>(x0s + chunk * 64 + 4 * tr);
            a0 = av.x; a1 = av.y; a2 = av.z; a3 = av.w;
        } else {           // P_ext[d][1024+q] = v[q]
            a0 = a1 = a2 = a3 = 1.f;
        }
#pragma unroll 8
        for (int q = 0; q < 32; ++q) {
            const float4 xv = *reinterpret_cast<const float4*>(x0s + q * 64 + 4 * tr);
            float pr[4] = {a0 * xv.x, a1 * xv.y, a2 * xv.z, a3 * xv.w};
            const float4 wa = *reinterpret_cast<const float4*>(shbuf + q * 128 + 8 * tc);
            const float4 wb = *reinterpret_cast<const float4*>(shbuf + q * 128 + 8 * tc + 4);
            float w[8] = {wa.x, wa.y, wa.z, wa.w, wb.x, wb.y, wb.z, wb.w};
#pragma unroll
            for (int i = 0; i < 4; ++i)
#pragma unroll
                for (int j = 0; j < 8; ++j) acc[i][j] += pr[i] * w[j];
        }
    }

    __syncthreads();  // all wch reads done; shbuf becomes accs
#pragma unroll
    for (int i = 0; i < 4; ++i)
#pragma unroll
        for (int j = 0; j < 8; ++j)
            shbuf[(4 * tr + i) * 129 + 8 * tc + j] = acc[i][j];
    __syncthreads();

    if (t < 64) {  // one lane per d-row; all in wave 0
        float s = 0.f;
#pragma unroll 8
        for (int h = 0; h < 64; ++h)
            s += (shbuf[t * 129 + h] + b1s[h]) * (w1s[h] + shbuf[t * 129 + 64 + h]);
#pragma unroll
        for (int m = 0; m < 32; ++m) s += rs[m] * x0s[m * 64 + t];
#pragma unroll
        for (int off = 32; off; off >>= 1) s += __shfl_down(s, off);
        if (t == 0) out[b] = cnst[0] + s;
    }
}

extern "C" void kernel_launch(void* const* d_in, const int* in_sizes, int n_in,
                              void* d_out, int out_size, void* d_ws, size_t ws_size,
                              hipStream_t stream) {
    const float* x0    = (const float*)d_in[0];
    const float* W1    = (const float*)d_in[1];
    const float* b1    = (const float*)d_in[2];
    const float* W2    = (const float*)d_in[3];
    const float* b2    = (const float*)d_in[4];
    const float* W3    = (const float*)d_in[5];
    const float* b3    = (const float*)d_in[6];
    const float* W_out = (const float*)d_in[7];
    const float* b_out = (const float*)d_in[8];

    float* ws    = (float*)d_ws;
    float* Wcat  = ws;              // 1056*128 = 135168 floats
    float* W3eff = ws + 135168;     // 64*32 = 2048
    float* rvec  = ws + 137216;     // 32
    float* cnst  = ws + 137248;     // 1
    float* out   = (float*)d_out;

    hipLaunchKernelGGL(pre_w3eff, dim3(8),    dim3(256), 0, stream, W3, W_out, W3eff);
    hipLaunchKernelGGL(pre_wcat,  dim3(528),  dim3(256), 0, stream, W1, W2, W_out, W3eff, Wcat);
    hipLaunchKernelGGL(pre_misc,  dim3(1),    dim3(64),  0, stream, b2, b3, W_out, b_out, W3eff, rvec, cnst);
    hipLaunchKernelGGL(cin_main,  dim3(2048), dim3(256), 0, stream, x0, Wcat, b1, W_out, rvec, cnst, out);
}

// Round 2
// 56.300 us; speedup vs baseline: 8.6580x; 8.6580x over previous
//
#include <hip/hip_runtime.h>

typedef _Float16 f16;
typedef _Float16 f16x2 __attribute__((ext_vector_type(2)));
typedef _Float16 f16x8 __attribute__((ext_vector_type(8)));
typedef float f32x4 __attribute__((ext_vector_type(4)));
typedef unsigned int u32;

union U2 { u32 u; f16x2 h; };
union AF { f16x8 v; u32 u[4]; };

// ---------------- pre kernels ----------------

__global__ void pre_w3eff(const float* __restrict__ W3,
                          const float* __restrict__ W_out,
                          float* __restrict__ W3eff) {
    int tid = blockIdx.x * blockDim.x + threadIdx.x;  // 2048
    int h = tid >> 5, m = tid & 31;
    float s = 0.f;
    for (int o = 0; o < 64; ++o)
        s += W_out[128 + o] * W3[(o * 64 + h) * 32 + m];
    W3eff[h * 32 + m] = s;
}

// Wfrag[c][t][lane][b] = Wcat[32c + kk(lane,b)][16t + (lane&15)] as fp16,
// kk = 4*(l>>4) + (b&3) + 16*(b>>2)   (mfma_16x16x32 B-fragment layout)
__global__ void pre_wfrag(const float* __restrict__ W1,
                          const float* __restrict__ W2,
                          const float* __restrict__ W_out,
                          const float* __restrict__ W3eff,
                          f16* __restrict__ Wfrag) {
    int tid = blockIdx.x * 256 + threadIdx.x;  // 33*8*64*8 = 135168
    int b = tid & 7, l = (tid >> 3) & 63, t4 = (tid >> 9) & 7, c = tid >> 12;
    int kk = 4 * ((l >> 4) & 3) + (b & 3) + 16 * (b >> 2);
    int j = 16 * t4 + (l & 15);
    int k = 32 * c + kk;
    float val = 0.f;
    if (k < 1024) {
        if (j < 64) {
            val = W1[j * 1024 + k];  // W1[j][p][q], k = 32p+q
        } else {
            int h = j - 64, q = k & 31, p = k >> 5;
            for (int o = 0; o < 64; ++o)
                val += W3eff[o * 32 + q] * W2[(o * 64 + h) * 32 + p];
        }
    } else {
        int mm = k - 1024;
        if (j >= 64) {
            int h = j - 64;
            for (int o = 0; o < 64; ++o)
                val += W_out[64 + o] * W2[(o * 64 + h) * 32 + mm];
        }
    }
    Wfrag[tid] = (f16)val;
}

__global__ void pre_misc(const float* __restrict__ b1,
                         const float* __restrict__ b2,
                         const float* __restrict__ b3,
                         const float* __restrict__ W_out,
                         const float* __restrict__ b_out,
                         const float* __restrict__ W3eff,
                         float* __restrict__ rvec,
                         float* __restrict__ cnst) {
    int t = threadIdx.x;  // 64
    if (t < 32) {
        float s = 0.f;
        for (int h = 0; h < 64; ++h) s += b2[h] * W3eff[h * 32 + t];
        rvec[t] = s;
    }
    if (t == 63) {
        float s = 0.f;
        for (int o = 0; o < 64; ++o)
            s += b1[o] * W_out[o] + b2[o] * W_out[64 + o] + b3[o] * W_out[128 + o];
        cnst[0] = b_out[0] + 64.f * s;
    }
}

// ---------------- main kernel ----------------

__device__ __forceinline__ void gld16(const void* g, void* l) {
    __builtin_amdgcn_global_load_lds(
        (const __attribute__((address_space(1))) u32*)g,
        (__attribute__((address_space(3))) u32*)l, 16, 0, 0);
}

__device__ __forceinline__ u32 dup16(float f) {
    U2 a; f16 h = (f16)f; a.h = f16x2{h, h}; return a.u;
}

// Block: 4 batches (256 rows) x 128 cols, 4 waves. Wave (wr,wc): rows
// [128wr,128wr+127], cols [64wc,64wc+63]. 8 strips x 4 col-tiles of 16x16x32.
__global__ __launch_bounds__(256, 2) void cin_main(
    const float* __restrict__ x0, const f16* __restrict__ Wfrag,
    const float* __restrict__ b1, const float* __restrict__ W_out,
    const float* __restrict__ rvec, const float* __restrict__ cnst,
    float* __restrict__ out) {
    __shared__ u32 xdup[4 * 32 * 64];   // 32 KB: {h,h} per x0 scalar, [bl][m][d]
    __shared__ f16 Bls[2 * 8 * 64 * 8]; // 16 KB: double-buffered W fragments
    __shared__ float eps[2][16 * 64];   // 8 KB: epilogue strip exchange
    __shared__ float b1s[64], w1s[64], rs[32], rvb[4], obuf[4][2];

    const int t = threadIdx.x;
    const int w = t >> 6, lane = t & 63;
    const int wr = w >> 1, wc = w & 1;
    const int g = (lane >> 4) & 3, l15 = lane & 15;
    const int blk = blockIdx.x;

    {  // stage x0 (4 batches, 32 KB fp32) -> xdup {h,h}
        const float4* src = reinterpret_cast<const float4*>(x0 + (size_t)blk * 8192);
#pragma unroll
        for (int it = 0; it < 8; ++it) {
            float4 v = src[it * 256 + t];
            uint4 d;
            d.x = dup16(v.x); d.y = dup16(v.y); d.z = dup16(v.z); d.w = dup16(v.w);
            *reinterpret_cast<uint4*>(&xdup[(it * 256 + t) * 4]) = d;
        }
    }
    if (t < 64) { b1s[t] = b1[t]; w1s[t] = W_out[t]; }
    if (t >= 64 && t < 96) rs[t - 64] = rvec[t - 64];
    __syncthreads();

    // xpre[s][i]: packed {x[m0][d], x[m0+1][d]} per strip, chunk-invariant
    f16x2 xp[8][4];
#pragma unroll
    for (int s = 0; s < 8; ++s) {
        int bl = 2 * wr + (s >> 2);
        int d = 16 * (s & 3) + l15;
#pragma unroll
        for (int i = 0; i < 4; ++i) {
            int m0 = 4 * g + 2 * (i & 1) + 16 * (i >> 1);
            u32 lo = xdup[bl * 2048 + m0 * 64 + d];
            u32 hi = xdup[bl * 2048 + (m0 + 1) * 64 + d];
            U2 p; p.u = (lo & 0xffffu) | (hi << 16);
            xp[s][i] = p.h;
        }
    }

    f32x4 acc[8][4];
#pragma unroll
    for (int s = 0; s < 8; ++s)
#pragma unroll
        for (int tt = 0; tt < 4; ++tt) acc[s][tt] = f32x4{0.f, 0.f, 0.f, 0.f};

    const char* WfB = reinterpret_cast<const char*>(Wfrag);
    char* BlB = reinterpret_cast<char*>(Bls);

#define STAGE(buf, ch)                                              \
    do {                                                            \
        const char* gs_ = WfB + (ch) * 8192 + w * 2048 + lane * 16; \
        char* ls_ = BlB + (buf) * 8192 + w * 2048;                  \
        gld16(gs_, ls_);                                            \
        gld16(gs_ + 1024, ls_ + 1024);                              \
    } while (0)

    STAGE(0, 0);
    __syncthreads();

    for (int c = 0; c < 32; ++c) {
        int cur = c & 1;
        STAGE(cur ^ 1, c + 1);
        f16x8 bf[4];
#pragma unroll
        for (int tt = 0; tt < 4; ++tt)
            bf[tt] = *reinterpret_cast<const f16x8*>(
                &Bls[cur * 4096 + ((wc * 4 + tt) * 64 + lane) * 8]);
#pragma unroll
        for (int s = 0; s < 8; ++s) {
            int bl = 2 * wr + (s >> 2);
            int d = 16 * (s & 3) + l15;
            U2 sc; sc.u = xdup[bl * 2048 + c * 64 + d];
            AF af;
#pragma unroll
            for (int i = 0; i < 4; ++i) {
                U2 pp; pp.h = sc.h * xp[s][i];  // v_pk_mul_f16
                af.u[i] = pp.u;
            }
#pragma unroll
            for (int tt = 0; tt < 4; ++tt)
                acc[s][tt] = __builtin_amdgcn_mfma_f32_16x16x32_f16(
                    af.v, bf[tt], acc[s][tt], 0, 0, 0);
        }
        __syncthreads();
    }
    {  // chunk 32: linear-v part, staged into buf 0 at c=31
        f16x8 bf[4];
#pragma unroll
        for (int tt = 0; tt < 4; ++tt)
            bf[tt] = *reinterpret_cast<const f16x8*>(
                &Bls[((wc * 4 + tt) * 64 + lane) * 8]);
#pragma unroll
        for (int s = 0; s < 8; ++s) {
            AF af;
#pragma unroll
            for (int i = 0; i < 4; ++i) { U2 pp; pp.h = xp[s][i]; af.u[i] = pp.u; }
#pragma unroll
            for (int tt = 0; tt < 4; ++tt)
                acc[s][tt] = __builtin_amdgcn_mfma_f32_16x16x32_f16(
                    af.v, bf[tt], acc[s][tt], 0, 0, 0);
        }
    }

    // ---- rv term: wave w handles batch w
    {
        int m = lane & 31, dh = lane >> 5;
        float sum = 0.f;
#pragma unroll
        for (int jj = 0; jj < 32; ++jj) {
            U2 v; v.u = xdup[w * 2048 + m * 64 + 2 * jj + dh];
            sum += (float)v.h[0];
        }
        sum *= rs[m];
#pragma unroll
        for (int off = 32; off; off >>= 1) sum += __shfl_xor(sum, off);
        if (lane == 0) rvb[w] = sum;
    }

    // ---- epilogue: s(b,d) = sum_h A1*(w1+A2) + b1*A2   (+ b1*w1 in cnst)
    float bs0 = 0.f, bs1 = 0.f;
#pragma unroll
    for (int s = 0; s < 8; ++s) {
        if (wc == 1) {
#pragma unroll
            for (int tt = 0; tt < 4; ++tt) {
                float w1v = w1s[16 * tt + l15];
                float b1v = b1s[16 * tt + l15];
#pragma unroll
                for (int r = 0; r < 4; ++r) {
                    float a = acc[s][tt][r];
                    eps[wr][(4 * g + r) * 64 + 16 * tt + l15] = a + w1v;
                    float term = b1v * a;
                    if (s < 4) bs0 += term; else bs1 += term;
                }
            }
        }
        __syncthreads();
        if (wc == 0) {
#pragma unroll
            for (int tt = 0; tt < 4; ++tt) {
#pragma unroll
                for (int r = 0; r < 4; ++r) {
                    float x2 = eps[wr][(4 * g + r) * 64 + 16 * tt + l15];
                    float term = acc[s][tt][r] * x2;
                    if (s < 4) bs0 += term; else bs1 += term;
                }
            }
        }
        __syncthreads();
    }
#pragma unroll
    for (int off = 32; off; off >>= 1) {
        bs0 += __shfl_xor(bs0, off);
        bs1 += __shfl_xor(bs1, off);
    }
    if (lane == 0) { obuf[w][0] = bs0; obuf[w][1] = bs1; }
    __syncthreads();
    if (t < 4) {
        int bt = t;
        out[blk * 4 + bt] = cnst[0] + rvb[bt] +
                            obuf[2 * (bt >> 1) + 0][bt & 1] +
                            obuf[2 * (bt >> 1) + 1][bt & 1];
    }
#undef STAGE
}

extern "C" void kernel_launch(void* const* d_in, const int* in_sizes, int n_in,
                              void* d_out, int out_size, void* d_ws, size_t ws_size,
                              hipStream_t stream) {
    const float* x0    = (const float*)d_in[0];
    const float* W1    = (const float*)d_in[1];
    const float* b1    = (const float*)d_in[2];
    const float* W2    = (const float*)d_in[3];
    const float* b2    = (const float*)d_in[4];
    const float* W3    = (const float*)d_in[5];
    const float* b3    = (const float*)d_in[6];
    const float* W_out = (const float*)d_in[7];
    const float* b_out = (const float*)d_in[8];

    char* wsb = (char*)d_ws;
    f16*   Wfrag = (f16*)wsb;                       // 135168 halves = 270336 B
    float* W3eff = (float*)(wsb + 270336);          // 2048 floats
    float* rvecp = W3eff + 2048;                    // 32
    float* cnstp = rvecp + 32;                      // 1
    float* outp  = (float*)d_out;

    hipLaunchKernelGGL(pre_w3eff, dim3(8),   dim3(256), 0, stream, W3, W_out, W3eff);
    hipLaunchKernelGGL(pre_wfrag, dim3(528), dim3(256), 0, stream, W1, W2, W_out, W3eff, Wfrag);
    hipLaunchKernelGGL(pre_misc,  dim3(1),   dim3(64),  0, stream, b1, b2, b3, W_out, b_out, W3eff, rvecp, cnstp);
    hipLaunchKernelGGL(cin_main,  dim3(512), dim3(256), 0, stream, x0, Wfrag, b1, W_out, rvecp, cnstp, outp);
}

// Round 3
// 51.272 us; speedup vs baseline: 9.5071x; 1.0981x over previous
//
#include <hip/hip_runtime.h>

typedef _Float16 f16;
typedef _Float16 f16x2 __attribute__((ext_vector_type(2)));
typedef _Float16 f16x8 __attribute__((ext_vector_type(8)));
typedef float f32x4 __attribute__((ext_vector_type(4)));
typedef unsigned int u32;

union U2 { u32 u; f16x2 h; };
union AF { f16x8 v; u32 u[4]; };

// ---------------- pre kernels ----------------

__global__ void pre_w3eff(const float* __restrict__ W3,
                          const float* __restrict__ W_out,
                          float* __restrict__ W3eff) {
    int tid = blockIdx.x * blockDim.x + threadIdx.x;  // 2048
    int h = tid >> 5, m = tid & 31;
    float s = 0.f;
    for (int o = 0; o < 64; ++o)
        s += W_out[128 + o] * W3[(o * 64 + h) * 32 + m];
    W3eff[h * 32 + m] = s;
}

// Wfrag[c][t][lane][b] = Wcat[32c + kk(lane,b)][16t + (lane&15)] as fp16,
// kk = 4*(l>>4) + (b&3) + 16*(b>>2)   (mfma_16x16x32 B-fragment layout)
__global__ void pre_wfrag(const float* __restrict__ W1,
                          const float* __restrict__ W2,
                          const float* __restrict__ W_out,
                          const float* __restrict__ W3eff,
                          f16* __restrict__ Wfrag) {
    int tid = blockIdx.x * 256 + threadIdx.x;  // 33*8*64*8 = 135168
    int b = tid & 7, l = (tid >> 3) & 63, t4 = (tid >> 9) & 7, c = tid >> 12;
    int kk = 4 * ((l >> 4) & 3) + (b & 3) + 16 * (b >> 2);
    int j = 16 * t4 + (l & 15);
    int k = 32 * c + kk;
    float val = 0.f;
    if (k < 1024) {
        if (j < 64) {
            val = W1[j * 1024 + k];  // W1[j][p][q], k = 32p+q
        } else {
            int h = j - 64, q = k & 31, p = k >> 5;
            for (int o = 0; o < 64; ++o)
                val += W3eff[o * 32 + q] * W2[(o * 64 + h) * 32 + p];
        }
    } else {
        int mm = k - 1024;
        if (j >= 64) {
            int h = j - 64;
            for (int o = 0; o < 64; ++o)
                val += W_out[64 + o] * W2[(o * 64 + h) * 32 + mm];
        }
    }
    Wfrag[tid] = (f16)val;
}

__global__ void pre_misc(const float* __restrict__ b1,
                         const float* __restrict__ b2,
                         const float* __restrict__ b3,
                         const float* __restrict__ W_out,
                         const float* __restrict__ b_out,
                         const float* __restrict__ W3eff,
                         float* __restrict__ rvec,
                         float* __restrict__ cnst) {
    int t = threadIdx.x;  // 64
    if (t < 32) {
        float s = 0.f;
        for (int h = 0; h < 64; ++h) s += b2[h] * W3eff[h * 32 + t];
        rvec[t] = s;
    }
    if (t == 63) {
        float s = 0.f;
        for (int o = 0; o < 64; ++o)
            s += b1[o] * W_out[o] + b2[o] * W_out[64 + o] + b3[o] * W_out[128 + o];
        cnst[0] = b_out[0] + 64.f * s;
    }
}

// ---------------- main kernel ----------------

__device__ __forceinline__ u32 dup16(float f) {
    U2 a; f16 h = (f16)f; a.h = f16x2{h, h}; return a.u;
}

// eps position swizzle: 2-way max bank aliasing (free)
#define EPOS(row, col) ((row) * 64 + (((col) + 4 * (row)) & 63))

// Block: 4 batches (256 rows) x 128 cols, 4 waves. Wave (wr,wc): rows
// [128wr,128wr+127], cols [64wc,64wc+63]. 8 strips x 4 col-tiles of 16x16x32.
// B fragments come straight from global (L2-resident) -> no main-loop barriers.
__global__ __launch_bounds__(256, 2) void cin_main(
    const float* __restrict__ x0, const f16* __restrict__ Wfrag,
    const float* __restrict__ b1, const float* __restrict__ W_out,
    const float* __restrict__ rvec, const float* __restrict__ cnst,
    float* __restrict__ out) {
    __shared__ u32 xdup[4 * 32 * 64];   // [bl][m][l][j] = dup16(x[bl][m][16j+l])
    __shared__ float eps[2][16 * 64];   // epilogue strip exchange (swizzled)
    __shared__ float b1s[64], w1s[64], rs[32], rvb[4], obuf[4][2];

    const int t = threadIdx.x;
    const int w = t >> 6, lane = t & 63;
    const int wr = w >> 1, wc = w & 1;
    const int g = (lane >> 4) & 3, l15 = lane & 15;
    const int blk = blockIdx.x;

    {  // stage x0 -> xdup, transposed-quad layout, conflict-free uint4 stores
        const float* src = x0 + (size_t)blk * 8192;
        const int l = t & 15;
        const int row = t >> 4;
#pragma unroll
        for (int it = 0; it < 8; ++it) {
            int rm = it * 16 + row;  // bl*32+m
            uint4 dv;
            dv.x = dup16(src[rm * 64 + 0  + l]);
            dv.y = dup16(src[rm * 64 + 16 + l]);
            dv.z = dup16(src[rm * 64 + 32 + l]);
            dv.w = dup16(src[rm * 64 + 48 + l]);
            *reinterpret_cast<uint4*>(&xdup[rm * 64 + l * 4]) = dv;
        }
    }
    if (t < 64) { b1s[t] = b1[t]; w1s[t] = W_out[t]; }
    if (t >= 64 && t < 96) rs[t - 64] = rvec[t - 64];
    __syncthreads();

    // xpre[s][i]: packed {x[m0][d], x[m0+1][d]} per strip, chunk-invariant
    f16x2 xp[8][4];
#pragma unroll
    for (int s = 0; s < 8; ++s) {
        int bl = 2 * wr + (s >> 2);
        int base = bl * 2048 + l15 * 4 + (s & 3);
#pragma unroll
        for (int i = 0; i < 4; ++i) {
            int m0 = 4 * g + 2 * (i & 1) + 16 * (i >> 1);
            u32 lo = xdup[base + m0 * 64];
            u32 hi = xdup[base + (m0 + 1) * 64];
            U2 p; p.u = (lo & 0xffffu) | (hi << 16);
            xp[s][i] = p.h;
        }
    }

    f32x4 acc[8][4];
#pragma unroll
    for (int s = 0; s < 8; ++s)
#pragma unroll
        for (int tt = 0; tt < 4; ++tt) acc[s][tt] = f32x4{0.f, 0.f, 0.f, 0.f};

    const f16x8* Wg = reinterpret_cast<const f16x8*>(Wfrag);
    f16x8 bf[4], bfn[4];
#pragma unroll
    for (int tt = 0; tt < 4; ++tt)
        bf[tt] = Wg[(wc * 4 + tt) * 64 + lane];

    for (int c = 0; c < 32; ++c) {
        // prefetch next chunk's B fragments (global, L2-hit)
#pragma unroll
        for (int tt = 0; tt < 4; ++tt)
            bfn[tt] = Wg[((c + 1) * 8 + wc * 4 + tt) * 64 + lane];
        // this chunk's x scalars: 2 conflict-free ds_read_b128
        uint4 q0 = *reinterpret_cast<const uint4*>(
            &xdup[(2 * wr) * 2048 + c * 64 + l15 * 4]);
        uint4 q1 = *reinterpret_cast<const uint4*>(
            &xdup[(2 * wr + 1) * 2048 + c * 64 + l15 * 4]);
        u32 qs[8];
        qs[0] = q0.x; qs[1] = q0.y; qs[2] = q0.z; qs[3] = q0.w;
        qs[4] = q1.x; qs[5] = q1.y; qs[6] = q1.z; qs[7] = q1.w;
#pragma unroll
        for (int s = 0; s < 8; ++s) {
            U2 sc; sc.u = qs[s];
            AF af;
#pragma unroll
            for (int i = 0; i < 4; ++i) {
                U2 pp; pp.h = sc.h * xp[s][i];  // v_pk_mul_f16
                af.u[i] = pp.u;
            }
#pragma unroll
            for (int tt = 0; tt < 4; ++tt)
                acc[s][tt] = __builtin_amdgcn_mfma_f32_16x16x32_f16(
                    af.v, bf[tt], acc[s][tt], 0, 0, 0);
        }
#pragma unroll
        for (int tt = 0; tt < 4; ++tt) bf[tt] = bfn[tt];
    }
    {  // chunk 32: linear-v part, A = xp directly
#pragma unroll
        for (int s = 0; s < 8; ++s) {
            AF af;
#pragma unroll
            for (int i = 0; i < 4; ++i) { U2 pp; pp.h = xp[s][i]; af.u[i] = pp.u; }
#pragma unroll
            for (int tt = 0; tt < 4; ++tt)
                acc[s][tt] = __builtin_amdgcn_mfma_f32_16x16x32_f16(
                    af.v, bf[tt], acc[s][tt], 0, 0, 0);
        }
    }

    // ---- rv term: wave w handles batch w; lane <-> d (conflict-free)
    {
        float sum = 0.f;
        int base = w * 2048 + (lane & 15) * 4 + (lane >> 4);
#pragma unroll
        for (int m = 0; m < 32; ++m) {
            U2 v; v.u = xdup[base + m * 64];
            sum += rs[m] * (float)v.h[0];
        }
#pragma unroll
        for (int off = 32; off; off >>= 1) sum += __shfl_xor(sum, off);
        if (lane == 0) rvb[w] = sum;
    }

    // ---- epilogue: s(b,d) = sum_h A1*(w1+A2) + b1*A2   (+ b1*w1 in cnst)
    float bs0 = 0.f, bs1 = 0.f;
#pragma unroll
    for (int s = 0; s < 8; ++s) {
        if (wc == 1) {
#pragma unroll
            for (int tt = 0; tt < 4; ++tt) {
                float w1v = w1s[16 * tt + l15];
                float b1v = b1s[16 * tt + l15];
#pragma unroll
                for (int r = 0; r < 4; ++r) {
                    float a = acc[s][tt][r];
                    eps[wr][EPOS(4 * g + r, 16 * tt + l15)] = a + w1v;
                    float term = b1v * a;
                    if (s < 4) bs0 += term; else bs1 += term;
                }
            }
        }
        __syncthreads();
        if (wc == 0) {
#pragma unroll
            for (int tt = 0; tt < 4; ++tt) {
#pragma unroll
                for (int r = 0; r < 4; ++r) {
                    float x2 = eps[wr][EPOS(4 * g + r, 16 * tt + l15)];
                    float term = acc[s][tt][r] * x2;
                    if (s < 4) bs0 += term; else bs1 += term;
                }
            }
        }
        __syncthreads();
    }
#pragma unroll
    for (int off = 32; off; off >>= 1) {
        bs0 += __shfl_xor(bs0, off);
        bs1 += __shfl_xor(bs1, off);
    }
    if (lane == 0) { obuf[w][0] = bs0; obuf[w][1] = bs1; }
    __syncthreads();
    if (t < 4) {
        int bt = t;
        out[blk * 4 + bt] = cnst[0] + rvb[bt] +
                            obuf[2 * (bt >> 1) + 0][bt & 1] +
                            obuf[2 * (bt >> 1) + 1][bt & 1];
    }
}

extern "C" void kernel_launch(void* const* d_in, const int* in_sizes, int n_in,
                              void* d_out, int out_size, void* d_ws, size_t ws_size,
                              hipStream_t stream) {
    const float* x0    = (const float*)d_in[0];
    const float* W1    = (const float*)d_in[1];
    const float* b1    = (const float*)d_in[2];
    const float* W2    = (const float*)d_in[3];
    const float* b2    = (const float*)d_in[4];
    const float* W3    = (const float*)d_in[5];
    const float* b3    = (const float*)d_in[6];
    const float* W_out = (const float*)d_in[7];
    const float* b_out = (const float*)d_in[8];

    char* wsb = (char*)d_ws;
    f16*   Wfrag = (f16*)wsb;                       // 135168 halves = 270336 B
    float* W3eff = (float*)(wsb + 270336);          // 2048 floats
    float* rvecp = W3eff + 2048;                    // 32
    float* cnstp = rvecp + 32;                      // 1
    float* outp  = (float*)d_out;

    hipLaunchKernelGGL(pre_w3eff, dim3(8),   dim3(256), 0, stream, W3, W_out, W3eff);
    hipLaunchKernelGGL(pre_wfrag, dim3(528), dim3(256), 0, stream, W1, W2, W_out, W3eff, Wfrag);
    hipLaunchKernelGGL(pre_misc,  dim3(1),   dim3(64),  0, stream, b1, b2, b3, W_out, b_out, W3eff, rvecp, cnstp);
    hipLaunchKernelGGL(cin_main,  dim3(512), dim3(256), 0, stream, x0, Wfrag, b1, W_out, rvecp, cnstp, outp);
}